// Round 3
// baseline (726.449 us; speedup 1.0000x reference)
//
#include <hip/hip_runtime.h>
#include <math.h>

typedef _Float16 half8 __attribute__((ext_vector_type(8)));
typedef _Float16 half4 __attribute__((ext_vector_type(4)));
typedef float f32x4 __attribute__((ext_vector_type(4)));

constexpr int IN    = 256;
constexpr int HEADS = 4;
constexpr int HID   = 64;
constexpr int NCLS  = 47;
constexpr int HD0   = 256;
constexpr int HD1   = 188;
constexpr float NEG_SLOPE = 0.2f;
constexpr int ND0 = 50000, ND1 = 10000;

static __device__ __forceinline__ float leaky(float x) {
    return x >= 0.f ? x : NEG_SLOPE * x;
}

// vT[h*IN + k] = sum_d W[k, h*D+d] * attn[h,d]
__global__ void make_vT(const float* __restrict__ W, const float* __restrict__ attn,
                        float* __restrict__ vT, int D) {
    int id = blockIdx.x * blockDim.x + threadIdx.x;
    if (id >= IN * HEADS) return;
    int k = id >> 2, h = id & 3;
    const float* wr = W + (size_t)k * (HEADS * D) + h * D;
    const float* ar = attn + h * D;
    float s = 0.f;
    for (int d = 0; d < D; ++d) s += wr[d] * ar[d];
    vT[h * IN + k] = s;
}

// Bt[n][k] = (n < N) ? (f16)W[k*N+n] : 0
__global__ void cvtB(const float* __restrict__ W, _Float16* __restrict__ Bt, int N, int BNp) {
    int id = blockIdx.x * 256 + threadIdx.x;
    if (id >= BNp * IN) return;
    int n = id / IN, k = id % IN;
    Bt[id] = (n < N) ? (_Float16)W[(size_t)k * N + n] : (_Float16)0.f;
}

// Pipelined MFMA GEMM: Z[M,NOUT] = A[M,256] @ Bt^T.  BM=128, BK=32, 8 waves.
// Double-buffered LDS, 1 barrier per K-step, next tile's global loads issued
// right after the barrier (latency hides under ds_read+MFMA).
// FUSE_EL: el = Z . attn_l per head (wave wn owns head wn when BN=256).
// FUSE_ER: er = A . vrT (fp32, accumulated during A staging), rows < Mr.
template <int BN, int NOUT, bool AHALF, bool ZHALF, bool FUSE_EL, bool FUSE_ER>
__global__ __launch_bounds__(512) void gemm_mfma(const void* __restrict__ Av,
        const _Float16* __restrict__ Bt, void* __restrict__ Z,
        const float* __restrict__ attn_l, float* __restrict__ el,
        const float* __restrict__ vrT, float* __restrict__ er, int M, int Mr) {
    constexpr int FN = BN / 64;
    __shared__ __align__(16) _Float16 As[2][128 * 40];
    __shared__ __align__(16) _Float16 Bs[2][BN * 40];
    const int t  = threadIdx.x;
    const int l  = t & 63, w = t >> 6;
    const int wm = w >> 2, wn = w & 3;
    const int lr = l & 15, lh = l >> 4;
    const int bm = blockIdx.x * 128;

    f32x4 zero = {0.f, 0.f, 0.f, 0.f};
    f32x4 acc[4][FN];
#pragma unroll
    for (int mi = 0; mi < 4; ++mi)
#pragma unroll
        for (int nj = 0; nj < FN; ++nj) acc[mi][nj] = zero;

    const int ar_ = t >> 2;
    const int ak_ = (t & 3) * 8;
    const int bc_ = t >> 1;
    const int bk_ = (t & 1) * 16;
    const int arow = bm + ar_;

    float s_afl[8];
    half8 s_avh;
    half8 s_b0, s_b1;
    float er_acc[4] = {0.f, 0.f, 0.f, 0.f};

    auto load_tile = [&](int k0) {
        if constexpr (AHALF) {
            if (arow < M) {
                s_avh = *(const half8*)((const _Float16*)Av + (size_t)arow * IN + k0 + ak_);
            } else {
#pragma unroll
                for (int i = 0; i < 8; ++i) s_avh[i] = (_Float16)0.f;
            }
        } else {
            if (arow < M) {
                const float* p = (const float*)Av + (size_t)arow * IN + k0 + ak_;
                float4 f0 = *(const float4*)p;
                float4 f1 = *(const float4*)(p + 4);
                s_afl[0] = f0.x; s_afl[1] = f0.y; s_afl[2] = f0.z; s_afl[3] = f0.w;
                s_afl[4] = f1.x; s_afl[5] = f1.y; s_afl[6] = f1.z; s_afl[7] = f1.w;
            } else {
#pragma unroll
                for (int i = 0; i < 8; ++i) s_afl[i] = 0.f;
            }
        }
        if (bc_ < BN) {
            const _Float16* p = Bt + (size_t)bc_ * IN + k0 + bk_;
            s_b0 = *(const half8*)p;
            s_b1 = *(const half8*)(p + 8);
        }
    };

    load_tile(0);
    int cur = 0;
#pragma unroll
    for (int tt = 0; tt < 8; ++tt) {
        const int k0 = tt * 32;
        // ---- write staged regs -> LDS[cur] ----
        if constexpr (AHALF) {
            *(half8*)&As[cur][ar_ * 40 + ak_] = s_avh;
        } else {
            half8 av;
#pragma unroll
            for (int i = 0; i < 8; ++i) av[i] = (_Float16)s_afl[i];
            *(half8*)&As[cur][ar_ * 40 + ak_] = av;
            if constexpr (FUSE_ER) {
#pragma unroll
                for (int h = 0; h < 4; ++h) {
                    const float* vp = vrT + h * IN + k0 + ak_;
#pragma unroll
                    for (int i = 0; i < 8; ++i)
                        er_acc[h] = fmaf(s_afl[i], vp[i], er_acc[h]);
                }
            }
        }
        if (bc_ < BN) {
            *(half8*)&Bs[cur][bc_ * 40 + bk_]      = s_b0;
            *(half8*)&Bs[cur][bc_ * 40 + bk_ + 8]  = s_b1;
        }
        __syncthreads();
        if (tt < 7) load_tile(k0 + 32);   // issue next tile's loads early
        half8 af[4], bf[FN];
#pragma unroll
        for (int mi = 0; mi < 4; ++mi)
            af[mi] = *(const half8*)&As[cur][(wm * 64 + mi * 16 + lr) * 40 + lh * 8];
#pragma unroll
        for (int nj = 0; nj < FN; ++nj)
            bf[nj] = *(const half8*)&Bs[cur][(wn * (16 * FN) + nj * 16 + lr) * 40 + lh * 8];
#pragma unroll
        for (int mi = 0; mi < 4; ++mi)
#pragma unroll
            for (int nj = 0; nj < FN; ++nj)
                acc[mi][nj] = __builtin_amdgcn_mfma_f32_16x16x32_f16(
                    af[mi], bf[nj], acc[mi][nj], 0, 0, 0);
        cur ^= 1;
    }

    // ---- Z store (D layout: row=(l>>4)*4+r, col=l&15) ----
#pragma unroll
    for (int mi = 0; mi < 4; ++mi) {
#pragma unroll
        for (int r = 0; r < 4; ++r) {
            int grow = bm + wm * 64 + mi * 16 + lh * 4 + r;
            if (grow < M) {
#pragma unroll
                for (int nj = 0; nj < FN; ++nj) {
                    int col = wn * (16 * FN) + nj * 16 + lr;
                    if (col < NOUT) {
                        if constexpr (ZHALF)
                            ((_Float16*)Z)[(size_t)grow * NOUT + col] = (_Float16)acc[mi][nj][r];
                        else
                            ((float*)Z)[(size_t)grow * NOUT + col] = acc[mi][nj][r];
                    }
                }
            }
        }
    }
    if constexpr (FUSE_EL) {
        float alv[FN];
#pragma unroll
        for (int nj = 0; nj < FN; ++nj) alv[nj] = attn_l[wn * (16 * FN) + nj * 16 + lr];
#pragma unroll
        for (int mi = 0; mi < 4; ++mi) {
#pragma unroll
            for (int r = 0; r < 4; ++r) {
                float s = 0.f;
#pragma unroll
                for (int nj = 0; nj < FN; ++nj) s += acc[mi][nj][r] * alv[nj];
                s += __shfl_xor(s, 1); s += __shfl_xor(s, 2);
                s += __shfl_xor(s, 4); s += __shfl_xor(s, 8);
                int grow = bm + wm * 64 + mi * 16 + lh * 4 + r;
                if (lr == 0 && grow < M) el[(size_t)grow * 4 + wn] = s;
            }
        }
    }
    if constexpr (FUSE_ER) {
#pragma unroll
        for (int h = 0; h < 4; ++h) {
            er_acc[h] += __shfl_xor(er_acc[h], 1);
            er_acc[h] += __shfl_xor(er_acc[h], 2);
        }
        if ((t & 3) == 0 && arow < Mr)
            *(float4*)(er + (size_t)arow * 4) =
                make_float4(er_acc[0], er_acc[1], er_acc[2], er_acc[3]);
    }
}

// el/er from f16 A; el for all rows, er for rows < Mr
__global__ __launch_bounds__(256) void gemv_lr_f16(const _Float16* __restrict__ A,
        const float* __restrict__ vlT, const float* __restrict__ vrT,
        float* __restrict__ el, float* __restrict__ er, int M, int Mr) {
    int wv = threadIdx.x >> 6, lane = threadIdx.x & 63;
    int row = blockIdx.x * 4 + wv;
    if (row >= M) return;
    half4 ah = *(const half4*)(A + (size_t)row * IN + lane * 4);
    float a0 = (float)ah[0], a1 = (float)ah[1], a2 = (float)ah[2], a3 = (float)ah[3];
    float sl[4], sr[4];
#pragma unroll
    for (int h = 0; h < 4; ++h) {
        float4 v = *(const float4*)(vlT + h * IN + lane * 4);
        sl[h] = a0 * v.x + a1 * v.y + a2 * v.z + a3 * v.w;
        float4 u = *(const float4*)(vrT + h * IN + lane * 4);
        sr[h] = a0 * u.x + a1 * u.y + a2 * u.z + a3 * u.w;
    }
#pragma unroll
    for (int off = 32; off; off >>= 1)
#pragma unroll
        for (int h = 0; h < 4; ++h) {
            sl[h] += __shfl_xor(sl[h], off);
            sr[h] += __shfl_xor(sr[h], off);
        }
    if (lane == 0) {
        *(float4*)(el + (size_t)row * 4) = make_float4(sl[0], sl[1], sl[2], sl[3]);
        if (row < Mr)
            *(float4*)(er + (size_t)row * 4) = make_float4(sr[0], sr[1], sr[2], sr[3]);
    }
}

__global__ void hist_k(const int* __restrict__ dst, int E, int* __restrict__ counts) {
    int i = blockIdx.x * blockDim.x + threadIdx.x;
    if (i < E) atomicAdd(&counts[dst[i]], 1);
}

// hierarchical block scan (1024 threads, shuffle-based)
__global__ __launch_bounds__(1024) void scan_k(const int* __restrict__ counts, int n,
        int* __restrict__ offsets, int* __restrict__ cursor) {
    __shared__ int wsum[16];
    int tid = threadIdx.x;
    int lane = tid & 63, wv = tid >> 6;
    int chunk = (n + 1023) >> 10;
    int b = tid * chunk, e = min(b + chunk, n);
    int s = 0;
    for (int i = b; i < e; ++i) s += counts[i];
    int v = s;
#pragma unroll
    for (int off = 1; off < 64; off <<= 1) {
        int u = __shfl_up(v, off);
        if (lane >= off) v += u;
    }
    if (lane == 63) wsum[wv] = v;
    __syncthreads();
    if (wv == 0 && lane < 16) {
        int tval = wsum[lane];
#pragma unroll
        for (int off = 1; off < 16; off <<= 1) {
            int u = __shfl_up(tval, off);
            if (lane >= off) tval += u;
        }
        wsum[lane] = tval;
    }
    __syncthreads();
    int base = (wv > 0 ? wsum[wv - 1] : 0) + v - s;   // exclusive prefix
    int run = base;
    for (int i = b; i < e; ++i) {
        int c = counts[i];
        offsets[i] = run;
        cursor[i] = run;
        run += c;
    }
    if (tid == 1023) offsets[n] = run;
}

__global__ void scatter_k(const int* __restrict__ src, const int* __restrict__ dst, int E,
        int* __restrict__ cursor, int* __restrict__ ssrc) {
    int i = blockIdx.x * blockDim.x + threadIdx.x;
    if (i < E) {
        int p = atomicAdd(&cursor[dst[i]], 1);
        ssrc[p] = src[i];
    }
}

// Layer-0 aggregation: 4 waves/block, 1 node/wave, index-prefetch + shfl broadcast
__global__ __launch_bounds__(256) void agg_l0(const int* __restrict__ ssrc,
        const int* __restrict__ offs, const float* __restrict__ el,
        const float* __restrict__ er, const _Float16* __restrict__ z,
        const float* __restrict__ bias, _Float16* __restrict__ h, int nd) {
    int wv = threadIdx.x >> 6, lane = threadIdx.x & 63;
    int d = blockIdx.x * 4 + wv;
    if (d >= nd) return;
    int head = lane >> 4;
    int beg = offs[d], end = offs[d + 1];
    float erh = er[(size_t)d * 4 + head];
    float ax = 0, ay = 0, az = 0, aw = 0, ssum = 0;
    for (int j0 = beg; j0 < end; j0 += 64) {
        int nn = min(64, end - j0);
        int myidx = (lane < nn) ? ssrc[j0 + lane] : 0;
        for (int j = 0; j < nn; ++j) {
            int s = __shfl(myidx, j);
            float e = el[(size_t)s * 4 + head] + erh;
            float wgt = __expf(leaky(e));
            ssum += wgt;
            half4 zv = *(const half4*)(z + (size_t)s * HD0 + lane * 4);
            ax += wgt * (float)zv[0]; ay += wgt * (float)zv[1];
            az += wgt * (float)zv[2]; aw += wgt * (float)zv[3];
        }
    }
    float inv = ssum > 0.f ? 1.f / ssum : 0.f;
    const float* b = bias + lane * 4;
    half4 o;
    o[0] = (_Float16)fmaxf(ax * inv + b[0], 0.f);
    o[1] = (_Float16)fmaxf(ay * inv + b[1], 0.f);
    o[2] = (_Float16)fmaxf(az * inv + b[2], 0.f);
    o[3] = (_Float16)fmaxf(aw * inv + b[3], 0.f);
    *(half4*)(h + (size_t)d * HD0 + lane * 4) = o;
}

// Layer-1 aggregation: 4 waves/block, 1 node/wave
__global__ __launch_bounds__(256) void agg_l1(const int* __restrict__ ssrc,
        const int* __restrict__ offs, const float* __restrict__ el,
        const float* __restrict__ er, const float* __restrict__ z,
        const float* __restrict__ bias, float* __restrict__ out, int nd) {
    int wv = threadIdx.x >> 6, lane = threadIdx.x & 63;
    int d = blockIdx.x * 4 + wv;
    if (d >= nd) return;
    int beg = offs[d], end = offs[d + 1];
    float4 er4 = *(const float4*)(er + (size_t)d * 4);
    const int f0 = lane, f1 = lane + 64, f2 = lane + 128;
    const int h0 = f0 / NCLS, h1 = f1 / NCLS;
    const bool has2 = f2 < HD1;
    const int h2 = has2 ? f2 / NCLS : 3;
    float a0 = 0, a1 = 0, a2 = 0;
    float s0 = 0, s1 = 0, s2 = 0, s3 = 0;
    for (int j0 = beg; j0 < end; j0 += 64) {
        int nn = min(64, end - j0);
        int myidx = (lane < nn) ? ssrc[j0 + lane] : 0;
        for (int j = 0; j < nn; ++j) {
            int s = __shfl(myidx, j);
            float4 e4 = *(const float4*)(el + (size_t)s * 4);
            float w0 = __expf(leaky(e4.x + er4.x));
            float w1 = __expf(leaky(e4.y + er4.y));
            float w2 = __expf(leaky(e4.z + er4.z));
            float w3 = __expf(leaky(e4.w + er4.w));
            s0 += w0; s1 += w1; s2 += w2; s3 += w3;
            const float* zr = z + (size_t)s * HD1;
            a0 += (h0 == 0 ? w0 : h0 == 1 ? w1 : h0 == 2 ? w2 : w3) * zr[f0];
            a1 += (h1 == 0 ? w0 : h1 == 1 ? w1 : h1 == 2 ? w2 : w3) * zr[f1];
            if (has2) a2 += (h2 == 0 ? w0 : h2 == 1 ? w1 : h2 == 2 ? w2 : w3) * zr[f2];
        }
    }
    float sa = h0 == 0 ? s0 : h0 == 1 ? s1 : h0 == 2 ? s2 : s3;
    float sb = h1 == 0 ? s0 : h1 == 1 ? s1 : h1 == 2 ? s2 : s3;
    float sc = h2 == 0 ? s0 : h2 == 1 ? s1 : h2 == 2 ? s2 : s3;
    float* orow = out + (size_t)d * HD1;
    orow[f0] = a0 * (sa > 0.f ? 1.f / sa : 0.f) + bias[f0];
    orow[f1] = a1 * (sb > 0.f ? 1.f / sb : 0.f) + bias[f1];
    if (has2) orow[f2] = a2 * (sc > 0.f ? 1.f / sc : 0.f) + bias[f2];
}

// mean over heads + log_softmax; one wave per node
__global__ __launch_bounds__(256) void final_k(const float* __restrict__ o1,
        float* __restrict__ y, int n) {
    int wave = threadIdx.x >> 6, lane = threadIdx.x & 63;
    int node = blockIdx.x * 4 + wave;
    if (node >= n) return;
    const float* r = o1 + (size_t)node * HD1;
    float vv = 0.f, v = -INFINITY;
    if (lane < NCLS) {
        vv = 0.25f * (r[lane] + r[lane + NCLS] + r[lane + 2 * NCLS] + r[lane + 3 * NCLS]);
        v = vv;
    }
    float mx = v;
#pragma unroll
    for (int off = 32; off; off >>= 1) mx = fmaxf(mx, __shfl_xor(mx, off));
    float p = (lane < NCLS) ? __expf(vv - mx) : 0.f;
    float sum = p;
#pragma unroll
    for (int off = 32; off; off >>= 1) sum += __shfl_xor(sum, off);
    if (lane < NCLS) y[(size_t)node * NCLS + lane] = vv - mx - logf(sum);
}

extern "C" void kernel_launch(void* const* d_in, const int* in_sizes, int n_in,
                              void* d_out, int out_size, void* d_ws, size_t ws_size,
                              hipStream_t stream) {
    const float* x    = (const float*)d_in[0];
    const int*   src0 = (const int*)d_in[1];
    const int*   dst0 = (const int*)d_in[2];
    const int*   src1 = (const int*)d_in[3];
    const int*   dst1 = (const int*)d_in[4];
    const float* W0s  = (const float*)d_in[7];
    const float* W0d  = (const float*)d_in[8];
    const float* al0  = (const float*)d_in[9];
    const float* ar0  = (const float*)d_in[10];
    const float* b0   = (const float*)d_in[11];
    const float* W1s  = (const float*)d_in[12];
    const float* W1d  = (const float*)d_in[13];
    const float* al1  = (const float*)d_in[14];
    const float* ar1  = (const float*)d_in[15];
    const float* b1   = (const float*)d_in[16];
    const int E0 = in_sizes[1], E1 = in_sizes[3];
    const int NS0 = in_sizes[0] / IN;

    char* p = (char*)d_ws;
    auto take = [&](size_t bytes) {
        char* r = p;
        p += (bytes + 255) & ~(size_t)255;
        return r;
    };
    _Float16* z0  = (_Float16*)take((size_t)NS0 * HD0 * 2);
    _Float16* h   = (_Float16*)take((size_t)ND0 * HD0 * 2);
    float*    z1  = (float*)take((size_t)ND0 * HD1 * 4);
    float*    o1  = (float*)take((size_t)ND1 * HD1 * 4);
    float*    el0 = (float*)take((size_t)NS0 * 4 * 4);
    float*    er0 = (float*)take((size_t)ND0 * 4 * 4);
    float*    el1 = (float*)take((size_t)ND0 * 4 * 4);
    float*    er1 = (float*)take((size_t)ND1 * 4 * 4);
    _Float16* B0t = (_Float16*)take((size_t)256 * IN * 2);
    _Float16* B1t = (_Float16*)take((size_t)192 * IN * 2);
    float*    vr0T = (float*)take(4 * IN * 4);
    float*    vl1T = (float*)take(4 * IN * 4);
    float*    vr1T = (float*)take(4 * IN * 4);
    int* counts0 = (int*)take((size_t)ND0 * 4);
    int* offs0   = (int*)take((size_t)(ND0 + 1) * 4);
    int* cur0    = (int*)take((size_t)ND0 * 4);
    int* ss0     = (int*)take((size_t)E0 * 4);
    int* counts1 = (int*)take((size_t)ND1 * 4);
    int* offs1   = (int*)take((size_t)(ND1 + 1) * 4);
    int* cur1    = (int*)take((size_t)ND1 * 4);
    int* ss1     = (int*)take((size_t)E1 * 4);

    hipMemsetAsync(counts0, 0, (size_t)ND0 * 4, stream);
    hipMemsetAsync(counts1, 0, (size_t)ND1 * 4, stream);

    make_vT<<<4, 256, 0, stream>>>(W0d, ar0, vr0T, HID);
    make_vT<<<4, 256, 0, stream>>>(W1s, al1, vl1T, NCLS);
    make_vT<<<4, 256, 0, stream>>>(W1d, ar1, vr1T, NCLS);
    cvtB<<<(256 * IN + 255) / 256, 256, 0, stream>>>(W0s, B0t, HD0, 256);
    cvtB<<<(192 * IN + 255) / 256, 256, 0, stream>>>(W1s, B1t, HD1, 192);

    // ---- layer 0 ----
    gemm_mfma<256, 256, false, true, true, true><<<(NS0 + 127) / 128, 512, 0, stream>>>(
        (const void*)x, B0t, (void*)z0, al0, el0, vr0T, er0, NS0, ND0);
    hist_k<<<(E0 + 255) / 256, 256, 0, stream>>>(dst0, E0, counts0);
    scan_k<<<1, 1024, 0, stream>>>(counts0, ND0, offs0, cur0);
    scatter_k<<<(E0 + 255) / 256, 256, 0, stream>>>(src0, dst0, E0, cur0, ss0);
    agg_l0<<<(ND0 + 3) / 4, 256, 0, stream>>>(ss0, offs0, el0, er0, z0, b0, h, ND0);

    // ---- layer 1 ----
    gemm_mfma<192, 188, true, false, false, false><<<(ND0 + 127) / 128, 512, 0, stream>>>(
        (const void*)h, B1t, (void*)z1, nullptr, nullptr, nullptr, nullptr, ND0, 0);
    gemv_lr_f16<<<(ND0 + 3) / 4, 256, 0, stream>>>(h, vl1T, vr1T, el1, er1, ND0, ND1);
    hist_k<<<(E1 + 255) / 256, 256, 0, stream>>>(dst1, E1, counts1);
    scan_k<<<1, 1024, 0, stream>>>(counts1, ND1, offs1, cur1);
    scatter_k<<<(E1 + 255) / 256, 256, 0, stream>>>(src1, dst1, E1, cur1, ss1);
    agg_l1<<<(ND1 + 3) / 4, 256, 0, stream>>>(ss1, offs1, el1, er1, z1, b1, o1, ND1);

    final_k<<<(ND1 + 3) / 4, 256, 0, stream>>>(o1, (float*)d_out, ND1);
}

// Round 4
// 379.565 us; speedup vs baseline: 1.9139x; 1.9139x over previous
//
#include <hip/hip_runtime.h>
#include <math.h>

typedef _Float16 half8 __attribute__((ext_vector_type(8)));
typedef _Float16 half4 __attribute__((ext_vector_type(4)));
typedef float f32x4 __attribute__((ext_vector_type(4)));

constexpr int IN    = 256;
constexpr int HEADS = 4;
constexpr int HID   = 64;
constexpr int NCLS  = 47;
constexpr int HD0   = 256;
constexpr int HD1   = 188;
constexpr float NEG_SLOPE = 0.2f;
constexpr int ND0 = 50000, ND1 = 10000;

static __device__ __forceinline__ float leaky(float x) {
    return x >= 0.f ? x : NEG_SLOPE * x;
}

__device__ __forceinline__ void gload16(const void* g, void* l) {
    __builtin_amdgcn_global_load_lds((const __attribute__((address_space(1))) void*)g,
                                     (__attribute__((address_space(3))) void*)l, 16, 0, 0);
}

// vT[h*IN + k] = sum_d W[k, h*D+d] * attn[h,d]
__global__ void make_vT(const float* __restrict__ W, const float* __restrict__ attn,
                        float* __restrict__ vT, int D) {
    int id = blockIdx.x * blockDim.x + threadIdx.x;
    if (id >= IN * HEADS) return;
    int k = id >> 2, h = id & 3;
    const float* wr = W + (size_t)k * (HEADS * D) + h * D;
    const float* ar = attn + h * D;
    float s = 0.f;
    for (int d = 0; d < D; ++d) s += wr[d] * ar[d];
    vT[h * IN + k] = s;
}

// Bt[n][k] = (n < N) ? (f16)W[k*N+n] : 0 ;  Bt is [256][IN]
__global__ void cvtB(const float* __restrict__ W, _Float16* __restrict__ Bt, int N) {
    int id = blockIdx.x * 256 + threadIdx.x;
    if (id >= 256 * IN) return;
    int n = id / IN, k = id % IN;
    Bt[id] = (n < N) ? (_Float16)W[(size_t)k * N + n] : (_Float16)0.f;
}

// MFMA GEMM: Z[M,NOUT] = A[M,256] @ Bt^T (Bt [256][256] f16 col-major weights).
// BM=128, BN=256, BK=32, 512 thr = 8 waves (2Mx4N).
// global_load_lds (async DMA, no reg payload) + LDS double-buffer + raw s_barrier
// + counted vmcnt (3 or 4, never 0 mid-loop). Both-sides 16B XOR swizzle:
//   A f32 tile rows 128B/8 slots: slot' = slot ^ (row&7)         -> 2-way free
//   f16 tile rows  64B/4 slots: slot' = slot ^ ((row>>1)&3)      -> 2-way free
template <bool AHALF, int NOUT, bool ZHALF, bool FUSE_EL>
__global__ __launch_bounds__(512) void gemm_mfma(const void* __restrict__ Av,
        const _Float16* __restrict__ Bt, void* __restrict__ Z,
        const float* __restrict__ attn_l, float* __restrict__ el, int M) {
    constexpr int ASZ = AHALF ? 8192 : 16384;
    __shared__ __align__(16) char As[2][ASZ];
    __shared__ __align__(16) char Bs[2][16384];
    const int t  = threadIdx.x;
    const int l  = t & 63, w = t >> 6;
    const int wm = w >> 2, wn = w & 3;
    const int lr = l & 15, lh = l >> 4;
    const int bm = blockIdx.x * 128;

    f32x4 acc[4][4];
#pragma unroll
    for (int mi = 0; mi < 4; ++mi)
#pragma unroll
        for (int nj = 0; nj < 4; ++nj) {
            acc[mi][nj][0] = 0.f; acc[mi][nj][1] = 0.f;
            acc[mi][nj][2] = 0.f; acc[mi][nj][3] = 0.f;
        }

    auto stage = [&](int buf, int k0) {
        // B: 1024 chunks (256 rows x 64B), 2 issues
#pragma unroll
        for (int i = 0; i < 2; ++i) {
            int c = w * 128 + i * 64 + l;
            int rB = c >> 2, sB = c & 3;
            int sp = sB ^ ((rB >> 1) & 3);
            gload16(Bt + (size_t)rB * IN + k0 + sp * 8,
                    &Bs[buf][(w * 128 + i * 64) * 16]);
        }
        if constexpr (AHALF) {
            // A f16: 512 chunks (128 rows x 64B), 1 issue
            int c = w * 64 + l;
            int r = c >> 2, s = c & 3;
            int sp = s ^ ((r >> 1) & 3);
            int row = bm + r; row = row < M ? row : M - 1;
            gload16((const _Float16*)Av + (size_t)row * IN + k0 + sp * 8,
                    &As[buf][(w * 64) * 16]);
        } else {
            // A f32: 1024 chunks (128 rows x 128B), 2 issues
#pragma unroll
            for (int i = 0; i < 2; ++i) {
                int c = w * 128 + i * 64 + l;
                int r = c >> 3, s = c & 7;
                int sp = s ^ (r & 7);
                int row = bm + r; row = row < M ? row : M - 1;
                gload16((const float*)Av + (size_t)row * IN + k0 + sp * 4,
                        &As[buf][(w * 128 + i * 64) * 16]);
            }
        }
    };

    stage(0, 0);
#pragma unroll
    for (int tt = 0; tt < 8; ++tt) {
        const int cur = tt & 1;
        if (tt < 7) {
            stage(cur ^ 1, (tt + 1) * 32);
            if constexpr (AHALF) asm volatile("s_waitcnt vmcnt(3)" ::: "memory");
            else                 asm volatile("s_waitcnt vmcnt(4)" ::: "memory");
        } else {
            asm volatile("s_waitcnt vmcnt(0)" ::: "memory");
        }
        __builtin_amdgcn_s_barrier();
        asm volatile("" ::: "memory");
        half8 af[4], bf[4];
#pragma unroll
        for (int mi = 0; mi < 4; ++mi) {
            int row = wm * 64 + mi * 16 + lr;
            if constexpr (AHALF) {
                af[mi] = *(const half8*)&As[cur][row * 64 + ((lh ^ ((row >> 1) & 3)) << 4)];
            } else {
                const char* base = &As[cur][row * 128];
                float4 fa0 = *(const float4*)(base + ((((lh * 2))     ^ (row & 7)) << 4));
                float4 fa1 = *(const float4*)(base + ((((lh * 2) + 1) ^ (row & 7)) << 4));
                half8 v;
                v[0] = (_Float16)fa0.x; v[1] = (_Float16)fa0.y;
                v[2] = (_Float16)fa0.z; v[3] = (_Float16)fa0.w;
                v[4] = (_Float16)fa1.x; v[5] = (_Float16)fa1.y;
                v[6] = (_Float16)fa1.z; v[7] = (_Float16)fa1.w;
                af[mi] = v;
            }
        }
#pragma unroll
        for (int nj = 0; nj < 4; ++nj) {
            int row = wn * 64 + nj * 16 + lr;
            bf[nj] = *(const half8*)&Bs[cur][row * 64 + ((lh ^ ((row >> 1) & 3)) << 4)];
        }
#pragma unroll
        for (int mi = 0; mi < 4; ++mi)
#pragma unroll
            for (int nj = 0; nj < 4; ++nj)
                acc[mi][nj] = __builtin_amdgcn_mfma_f32_16x16x32_f16(
                    af[mi], bf[nj], acc[mi][nj], 0, 0, 0);
        asm volatile("" ::: "memory");
        __builtin_amdgcn_s_barrier();
    }

    // Z store (D layout: row=(l>>4)*4+r, col=l&15)
#pragma unroll
    for (int mi = 0; mi < 4; ++mi) {
#pragma unroll
        for (int r = 0; r < 4; ++r) {
            int grow = bm + wm * 64 + mi * 16 + lh * 4 + r;
            if (grow < M) {
#pragma unroll
                for (int nj = 0; nj < 4; ++nj) {
                    int col = wn * 64 + nj * 16 + lr;
                    if (col < NOUT) {
                        if constexpr (ZHALF)
                            ((_Float16*)Z)[(size_t)grow * NOUT + col] = (_Float16)acc[mi][nj][r];
                        else
                            ((float*)Z)[(size_t)grow * NOUT + col] = acc[mi][nj][r];
                    }
                }
            }
        }
    }
    if constexpr (FUSE_EL) {
        float alv[4];
#pragma unroll
        for (int nj = 0; nj < 4; ++nj) alv[nj] = attn_l[wn * 64 + nj * 16 + lr];
#pragma unroll
        for (int mi = 0; mi < 4; ++mi) {
#pragma unroll
            for (int r = 0; r < 4; ++r) {
                float s = 0.f;
#pragma unroll
                for (int nj = 0; nj < 4; ++nj) s += acc[mi][nj][r] * alv[nj];
                s += __shfl_xor(s, 1); s += __shfl_xor(s, 2);
                s += __shfl_xor(s, 4); s += __shfl_xor(s, 8);
                int grow = bm + wm * 64 + mi * 16 + lh * 4 + r;
                if (lr == 0 && grow < M) el[(size_t)grow * 4 + wn] = s;
            }
        }
    }
}

// er[m,h] = x[m,:] @ vrT[h,:]  (fp32 A); one wave per row
__global__ __launch_bounds__(256) void gemv_er_f32(const float* __restrict__ A,
        const float* __restrict__ vrT, float* __restrict__ er, int M) {
    int wv = threadIdx.x >> 6, lane = threadIdx.x & 63;
    int row = blockIdx.x * 4 + wv;
    if (row >= M) return;
    float4 xa = *(const float4*)(A + (size_t)row * IN + lane * 4);
    float s[4];
#pragma unroll
    for (int h = 0; h < 4; ++h) {
        float4 v = *(const float4*)(vrT + h * IN + lane * 4);
        s[h] = xa.x * v.x + xa.y * v.y + xa.z * v.z + xa.w * v.w;
    }
#pragma unroll
    for (int off = 32; off; off >>= 1)
#pragma unroll
        for (int h = 0; h < 4; ++h) s[h] += __shfl_xor(s[h], off);
    if (lane == 0) *(float4*)(er + (size_t)row * 4) = make_float4(s[0], s[1], s[2], s[3]);
}

// el/er from f16 A; el for all rows, er for rows < Mr
__global__ __launch_bounds__(256) void gemv_lr_f16(const _Float16* __restrict__ A,
        const float* __restrict__ vlT, const float* __restrict__ vrT,
        float* __restrict__ el, float* __restrict__ er, int M, int Mr) {
    int wv = threadIdx.x >> 6, lane = threadIdx.x & 63;
    int row = blockIdx.x * 4 + wv;
    if (row >= M) return;
    half4 ah = *(const half4*)(A + (size_t)row * IN + lane * 4);
    float a0 = (float)ah[0], a1 = (float)ah[1], a2 = (float)ah[2], a3 = (float)ah[3];
    float sl[4], sr[4];
#pragma unroll
    for (int h = 0; h < 4; ++h) {
        float4 v = *(const float4*)(vlT + h * IN + lane * 4);
        sl[h] = a0 * v.x + a1 * v.y + a2 * v.z + a3 * v.w;
        float4 u = *(const float4*)(vrT + h * IN + lane * 4);
        sr[h] = a0 * u.x + a1 * u.y + a2 * u.z + a3 * u.w;
    }
#pragma unroll
    for (int off = 32; off; off >>= 1)
#pragma unroll
        for (int h = 0; h < 4; ++h) {
            sl[h] += __shfl_xor(sl[h], off);
            sr[h] += __shfl_xor(sr[h], off);
        }
    if (lane == 0) {
        *(float4*)(el + (size_t)row * 4) = make_float4(sl[0], sl[1], sl[2], sl[3]);
        if (row < Mr)
            *(float4*)(er + (size_t)row * 4) = make_float4(sr[0], sr[1], sr[2], sr[3]);
    }
}

__global__ void hist_k(const int* __restrict__ dst, int E, int* __restrict__ counts) {
    int i = blockIdx.x * blockDim.x + threadIdx.x;
    if (i < E) atomicAdd(&counts[dst[i]], 1);
}

// ---- 3-kernel parallel exclusive scan over counts[0..n) ----
__global__ __launch_bounds__(256) void scan1_k(const int* __restrict__ counts, int n,
                                               int* __restrict__ part) {
    __shared__ int ws[4];
    int i = blockIdx.x * 256 + threadIdx.x;
    int lane = threadIdx.x & 63, wv = threadIdx.x >> 6;
    int s = (i < n) ? counts[i] : 0;
#pragma unroll
    for (int off = 32; off; off >>= 1) s += __shfl_xor(s, off);
    if (lane == 0) ws[wv] = s;
    __syncthreads();
    if (threadIdx.x == 0) part[blockIdx.x] = ws[0] + ws[1] + ws[2] + ws[3];
}

__global__ __launch_bounds__(256) void scan2_k(int* __restrict__ part, int nb) {
    __shared__ int ws[4];
    int tid = threadIdx.x, lane = tid & 63, wv = tid >> 6;
    int v = (tid < nb) ? part[tid] : 0;
    int x = v;
#pragma unroll
    for (int off = 1; off < 64; off <<= 1) {
        int u = __shfl_up(x, off);
        if (lane >= off) x += u;
    }
    if (lane == 63) ws[wv] = x;
    __syncthreads();
    int base = 0;
    for (int k = 0; k < wv; ++k) base += ws[k];
    if (tid < nb) part[tid] = base + x - v;   // exclusive
}

__global__ __launch_bounds__(256) void scan3_k(const int* __restrict__ counts, int n,
        const int* __restrict__ part, int* __restrict__ offsets, int* __restrict__ cursor) {
    __shared__ int ws[4];
    int i = blockIdx.x * 256 + threadIdx.x;
    int lane = threadIdx.x & 63, wv = threadIdx.x >> 6;
    int v = (i < n) ? counts[i] : 0;
    int x = v;
#pragma unroll
    for (int off = 1; off < 64; off <<= 1) {
        int u = __shfl_up(x, off);
        if (lane >= off) x += u;
    }
    if (lane == 63) ws[wv] = x;
    __syncthreads();
    int base = part[blockIdx.x];
    for (int k = 0; k < wv; ++k) base += ws[k];
    int off_ = base + x - v;
    if (i < n) { offsets[i] = off_; cursor[i] = off_; }
    if (i == n - 1) offsets[n] = off_ + v;
}

__global__ void scatter_k(const int* __restrict__ src, const int* __restrict__ dst, int E,
        int* __restrict__ cursor, int* __restrict__ ssrc) {
    int i = blockIdx.x * blockDim.x + threadIdx.x;
    if (i < E) {
        int p = atomicAdd(&cursor[dst[i]], 1);
        ssrc[p] = src[i];
    }
}

// Layer-0 aggregation: 4 waves/block, 1 node/wave, index-prefetch + shfl broadcast
__global__ __launch_bounds__(256) void agg_l0(const int* __restrict__ ssrc,
        const int* __restrict__ offs, const float* __restrict__ el,
        const float* __restrict__ er, const _Float16* __restrict__ z,
        const float* __restrict__ bias, _Float16* __restrict__ h, int nd) {
    int wv = threadIdx.x >> 6, lane = threadIdx.x & 63;
    int d = blockIdx.x * 4 + wv;
    if (d >= nd) return;
    int head = lane >> 4;
    int beg = offs[d], end = offs[d + 1];
    float erh = er[(size_t)d * 4 + head];
    float ax = 0, ay = 0, az = 0, aw = 0, ssum = 0;
    for (int j0 = beg; j0 < end; j0 += 64) {
        int nn = min(64, end - j0);
        int myidx = (lane < nn) ? ssrc[j0 + lane] : 0;
        for (int j = 0; j < nn; ++j) {
            int s = __shfl(myidx, j);
            float e = el[(size_t)s * 4 + head] + erh;
            float wgt = __expf(leaky(e));
            ssum += wgt;
            half4 zv = *(const half4*)(z + (size_t)s * HD0 + lane * 4);
            ax += wgt * (float)zv[0]; ay += wgt * (float)zv[1];
            az += wgt * (float)zv[2]; aw += wgt * (float)zv[3];
        }
    }
    float inv = ssum > 0.f ? 1.f / ssum : 0.f;
    const float* b = bias + lane * 4;
    half4 o;
    o[0] = (_Float16)fmaxf(ax * inv + b[0], 0.f);
    o[1] = (_Float16)fmaxf(ay * inv + b[1], 0.f);
    o[2] = (_Float16)fmaxf(az * inv + b[2], 0.f);
    o[3] = (_Float16)fmaxf(aw * inv + b[3], 0.f);
    *(half4*)(h + (size_t)d * HD0 + lane * 4) = o;
}

// Layer-1 aggregation: 4 waves/block, 1 node/wave
__global__ __launch_bounds__(256) void agg_l1(const int* __restrict__ ssrc,
        const int* __restrict__ offs, const float* __restrict__ el,
        const float* __restrict__ er, const float* __restrict__ z,
        const float* __restrict__ bias, float* __restrict__ out, int nd) {
    int wv = threadIdx.x >> 6, lane = threadIdx.x & 63;
    int d = blockIdx.x * 4 + wv;
    if (d >= nd) return;
    int beg = offs[d], end = offs[d + 1];
    float4 er4 = *(const float4*)(er + (size_t)d * 4);
    const int f0 = lane, f1 = lane + 64, f2 = lane + 128;
    const int h0 = f0 / NCLS, h1 = f1 / NCLS;
    const bool has2 = f2 < HD1;
    const int h2 = has2 ? f2 / NCLS : 3;
    float a0 = 0, a1 = 0, a2 = 0;
    float s0 = 0, s1 = 0, s2 = 0, s3 = 0;
    for (int j0 = beg; j0 < end; j0 += 64) {
        int nn = min(64, end - j0);
        int myidx = (lane < nn) ? ssrc[j0 + lane] : 0;
        for (int j = 0; j < nn; ++j) {
            int s = __shfl(myidx, j);
            float4 e4 = *(const float4*)(el + (size_t)s * 4);
            float w0 = __expf(leaky(e4.x + er4.x));
            float w1 = __expf(leaky(e4.y + er4.y));
            float w2 = __expf(leaky(e4.z + er4.z));
            float w3 = __expf(leaky(e4.w + er4.w));
            s0 += w0; s1 += w1; s2 += w2; s3 += w3;
            const float* zr = z + (size_t)s * HD1;
            a0 += (h0 == 0 ? w0 : h0 == 1 ? w1 : h0 == 2 ? w2 : w3) * zr[f0];
            a1 += (h1 == 0 ? w0 : h1 == 1 ? w1 : h1 == 2 ? w2 : w3) * zr[f1];
            if (has2) a2 += (h2 == 0 ? w0 : h2 == 1 ? w1 : h2 == 2 ? w2 : w3) * zr[f2];
        }
    }
    float sa = h0 == 0 ? s0 : h0 == 1 ? s1 : h0 == 2 ? s2 : s3;
    float sb = h1 == 0 ? s0 : h1 == 1 ? s1 : h1 == 2 ? s2 : s3;
    float sc = h2 == 0 ? s0 : h2 == 1 ? s1 : h2 == 2 ? s2 : s3;
    float* orow = out + (size_t)d * HD1;
    orow[f0] = a0 * (sa > 0.f ? 1.f / sa : 0.f) + bias[f0];
    orow[f1] = a1 * (sb > 0.f ? 1.f / sb : 0.f) + bias[f1];
    if (has2) orow[f2] = a2 * (sc > 0.f ? 1.f / sc : 0.f) + bias[f2];
}

// mean over heads + log_softmax; one wave per node
__global__ __launch_bounds__(256) void final_k(const float* __restrict__ o1,
        float* __restrict__ y, int n) {
    int wave = threadIdx.x >> 6, lane = threadIdx.x & 63;
    int node = blockIdx.x * 4 + wave;
    if (node >= n) return;
    const float* r = o1 + (size_t)node * HD1;
    float vv = 0.f, v = -INFINITY;
    if (lane < NCLS) {
        vv = 0.25f * (r[lane] + r[lane + NCLS] + r[lane + 2 * NCLS] + r[lane + 3 * NCLS]);
        v = vv;
    }
    float mx = v;
#pragma unroll
    for (int off = 32; off; off >>= 1) mx = fmaxf(mx, __shfl_xor(mx, off));
    float p = (lane < NCLS) ? __expf(vv - mx) : 0.f;
    float sum = p;
#pragma unroll
    for (int off = 32; off; off >>= 1) sum += __shfl_xor(sum, off);
    if (lane < NCLS) y[(size_t)node * NCLS + lane] = vv - mx - logf(sum);
}

extern "C" void kernel_launch(void* const* d_in, const int* in_sizes, int n_in,
                              void* d_out, int out_size, void* d_ws, size_t ws_size,
                              hipStream_t stream) {
    const float* x    = (const float*)d_in[0];
    const int*   src0 = (const int*)d_in[1];
    const int*   dst0 = (const int*)d_in[2];
    const int*   src1 = (const int*)d_in[3];
    const int*   dst1 = (const int*)d_in[4];
    const float* W0s  = (const float*)d_in[7];
    const float* W0d  = (const float*)d_in[8];
    const float* al0  = (const float*)d_in[9];
    const float* ar0  = (const float*)d_in[10];
    const float* b0   = (const float*)d_in[11];
    const float* W1s  = (const float*)d_in[12];
    const float* W1d  = (const float*)d_in[13];
    const float* al1  = (const float*)d_in[14];
    const float* ar1  = (const float*)d_in[15];
    const float* b1   = (const float*)d_in[16];
    const int E0 = in_sizes[1], E1 = in_sizes[3];
    const int NS0 = in_sizes[0] / IN;

    char* p = (char*)d_ws;
    auto take = [&](size_t bytes) {
        char* r = p;
        p += (bytes + 255) & ~(size_t)255;
        return r;
    };
    _Float16* z0  = (_Float16*)take((size_t)NS0 * HD0 * 2);
    _Float16* h   = (_Float16*)take((size_t)ND0 * HD0 * 2);
    float*    z1  = (float*)take((size_t)ND0 * HD1 * 4);
    float*    o1  = (float*)take((size_t)ND1 * HD1 * 4);
    float*    el0 = (float*)take((size_t)NS0 * 4 * 4);
    float*    er0 = (float*)take((size_t)ND0 * 4 * 4);
    float*    el1 = (float*)take((size_t)ND0 * 4 * 4);
    float*    er1 = (float*)take((size_t)ND1 * 4 * 4);
    _Float16* B0t = (_Float16*)take((size_t)256 * IN * 2);
    _Float16* B1t = (_Float16*)take((size_t)256 * IN * 2);
    float*    vr0T = (float*)take(4 * IN * 4);
    float*    vl1T = (float*)take(4 * IN * 4);
    float*    vr1T = (float*)take(4 * IN * 4);
    int* counts0 = (int*)take((size_t)ND0 * 4);
    int* offs0   = (int*)take((size_t)(ND0 + 1) * 4);
    int* cur0    = (int*)take((size_t)ND0 * 4);
    int* ss0     = (int*)take((size_t)E0 * 4);
    int* counts1 = (int*)take((size_t)ND1 * 4);
    int* offs1   = (int*)take((size_t)(ND1 + 1) * 4);
    int* cur1    = (int*)take((size_t)ND1 * 4);
    int* ss1     = (int*)take((size_t)E1 * 4);
    int* part0   = (int*)take(256 * 4);
    int* part1   = (int*)take(256 * 4);

    const int NB0 = (ND0 + 255) / 256, NB1 = (ND1 + 255) / 256;

    hipMemsetAsync(counts0, 0, (size_t)ND0 * 4, stream);
    hipMemsetAsync(counts1, 0, (size_t)ND1 * 4, stream);

    make_vT<<<4, 256, 0, stream>>>(W0d, ar0, vr0T, HID);
    make_vT<<<4, 256, 0, stream>>>(W1s, al1, vl1T, NCLS);
    make_vT<<<4, 256, 0, stream>>>(W1d, ar1, vr1T, NCLS);
    cvtB<<<256, 256, 0, stream>>>(W0s, B0t, HD0);
    cvtB<<<256, 256, 0, stream>>>(W1s, B1t, HD1);

    // ---- layer 0 ----
    gemm_mfma<false, 256, true, true><<<(NS0 + 127) / 128, 512, 0, stream>>>(
        (const void*)x, B0t, (void*)z0, al0, el0, NS0);
    gemv_er_f32<<<(ND0 + 3) / 4, 256, 0, stream>>>(x, vr0T, er0, ND0);
    hist_k<<<(E0 + 255) / 256, 256, 0, stream>>>(dst0, E0, counts0);
    scan1_k<<<NB0, 256, 0, stream>>>(counts0, ND0, part0);
    scan2_k<<<1, 256, 0, stream>>>(part0, NB0);
    scan3_k<<<NB0, 256, 0, stream>>>(counts0, ND0, part0, offs0, cur0);
    scatter_k<<<(E0 + 255) / 256, 256, 0, stream>>>(src0, dst0, E0, cur0, ss0);
    agg_l0<<<(ND0 + 3) / 4, 256, 0, stream>>>(ss0, offs0, el0, er0, z0, b0, h, ND0);

    // ---- layer 1 ----
    gemm_mfma<true, 188, false, false><<<(ND0 + 127) / 128, 512, 0, stream>>>(
        (const void*)h, B1t, (void*)z1, nullptr, nullptr, ND0);
    gemv_lr_f16<<<(ND0 + 3) / 4, 256, 0, stream>>>(h, vl1T, vr1T, el1, er1, ND0, ND1);
    hist_k<<<(E1 + 255) / 256, 256, 0, stream>>>(dst1, E1, counts1);
    scan1_k<<<NB1, 256, 0, stream>>>(counts1, ND1, part1);
    scan2_k<<<1, 256, 0, stream>>>(part1, NB1);
    scan3_k<<<NB1, 256, 0, stream>>>(counts1, ND1, part1, offs1, cur1);
    scatter_k<<<(E1 + 255) / 256, 256, 0, stream>>>(src1, dst1, E1, cur1, ss1);
    agg_l1<<<(ND1 + 3) / 4, 256, 0, stream>>>(ss1, offs1, el1, er1, z1, b1, o1, ND1);

    final_k<<<(ND1 + 3) / 4, 256, 0, stream>>>(o1, (float*)d_out, ND1);
}

// Round 5
// 333.053 us; speedup vs baseline: 2.1812x; 1.1397x over previous
//
#include <hip/hip_runtime.h>
#include <math.h>

typedef _Float16 half8 __attribute__((ext_vector_type(8)));
typedef _Float16 half4 __attribute__((ext_vector_type(4)));
typedef float f32x4 __attribute__((ext_vector_type(4)));

constexpr int IN    = 256;
constexpr int HEADS = 4;
constexpr int HID   = 64;
constexpr int NCLS  = 47;
constexpr int HD0   = 256;
constexpr int HD1   = 188;
constexpr float NEG_SLOPE = 0.2f;
constexpr int ND0 = 50000, ND1 = 10000;

static __device__ __forceinline__ float leaky(float x) {
    return x >= 0.f ? x : NEG_SLOPE * x;
}

__device__ __forceinline__ void gload16(const void* g, void* l) {
    __builtin_amdgcn_global_load_lds((const __attribute__((address_space(1))) void*)g,
                                     (__attribute__((address_space(3))) void*)l, 16, 0, 0);
}

// vT[h*IN + k] = sum_d W[k, h*D+d] * attn[h,d]
__global__ void make_vT(const float* __restrict__ W, const float* __restrict__ attn,
                        float* __restrict__ vT, int D) {
    int id = blockIdx.x * blockDim.x + threadIdx.x;
    if (id >= IN * HEADS) return;
    int k = id >> 2, h = id & 3;
    const float* wr = W + (size_t)k * (HEADS * D) + h * D;
    const float* ar = attn + h * D;
    float s = 0.f;
    for (int d = 0; d < D; ++d) s += wr[d] * ar[d];
    vT[h * IN + k] = s;
}

// Bt[n][k] = (n < N) ? (f16)W[k*N+n] : 0 ;  Bt is [BROWS][IN]
__global__ void cvtB(const float* __restrict__ W, _Float16* __restrict__ Bt, int N, int BROWS) {
    int id = blockIdx.x * 256 + threadIdx.x;
    if (id >= BROWS * IN) return;
    int n = id / IN, k = id % IN;
    Bt[id] = (n < N) ? (_Float16)W[(size_t)k * N + n] : (_Float16)0.f;
}

// Streaming MFMA GEMM for small B: entire B (BCOLS x 256 f16) lives in LDS,
// loaded once per block; then ZERO barriers. Each of 8 waves owns 16 output
// rows: whole A row-tile prefetched to registers (16 outstanding loads/lane),
// 8 K-steps x FN MFMA against LDS B. B slot swizzle c(r)=((r&15)<<1)^((r>>4)&1)
// -> exactly 2 lanes/bank-group on ds_read_b128 (free).
// FEL: 0 none; 1 = el += acc*attn (head = col/64); 2 = el (head = col/47).
template <bool AHALF, int BCOLS, int NOUT, bool ZHALF, int FEL>
__global__ __launch_bounds__(512) void gemm_stream(const void* __restrict__ Av,
        const _Float16* __restrict__ Bt, void* __restrict__ Z,
        const float* __restrict__ attn_flat, float* __restrict__ el, int M) {
    constexpr int FN = BCOLS / 16;
    __shared__ __align__(16) _Float16 Bs[BCOLS * 256];
    const int t = threadIdx.x;
    const int l = t & 63, w = t >> 6;
    const int lr = l & 15, lh = l >> 4;

    // ---- stage B (once) ----
    constexpr int ITERS = (BCOLS * 32) / 512;
#pragma unroll
    for (int it = 0; it < ITERS; ++it) {
        int c = it * 512 + t;
        int r = c >> 5, s = c & 31;
        int cs = s ^ (((r & 15) << 1) ^ ((r >> 4) & 1));
        gload16(Bt + (size_t)r * IN + cs * 8, (char*)Bs + (it * 512 + w * 64) * 16);
    }
    __syncthreads();   // drains vmcnt + barrier; last sync in the kernel

    const int R0 = blockIdx.x * 128 + w * 16;
    int arow = R0 + lr; if (arow >= M) arow = M - 1;

    f32x4 acc[FN];
#pragma unroll
    for (int nj = 0; nj < FN; ++nj) {
        acc[nj][0] = 0.f; acc[nj][1] = 0.f; acc[nj][2] = 0.f; acc[nj][3] = 0.f;
    }

    half8 av[8];
    float4 a0[8], a1[8];
    if constexpr (AHALF) {
        const _Float16* ap = (const _Float16*)Av + (size_t)arow * IN + lh * 8;
#pragma unroll
        for (int tt = 0; tt < 8; ++tt) av[tt] = *(const half8*)(ap + tt * 32);
    } else {
        const float* ap = (const float*)Av + (size_t)arow * IN + lh * 8;
#pragma unroll
        for (int tt = 0; tt < 8; ++tt) {
            a0[tt] = *(const float4*)(ap + tt * 32);
            a1[tt] = *(const float4*)(ap + tt * 32 + 4);
        }
    }

    const int swz_l = lr << 1;
#pragma unroll
    for (int tt = 0; tt < 8; ++tt) {
        half8 af;
        if constexpr (AHALF) {
            af = av[tt];
        } else {
            af[0] = (_Float16)a0[tt].x; af[1] = (_Float16)a0[tt].y;
            af[2] = (_Float16)a0[tt].z; af[3] = (_Float16)a0[tt].w;
            af[4] = (_Float16)a1[tt].x; af[5] = (_Float16)a1[tt].y;
            af[6] = (_Float16)a1[tt].z; af[7] = (_Float16)a1[tt].w;
        }
#pragma unroll
        for (int nj = 0; nj < FN; ++nj) {
            int colr = nj * 16 + lr;
            int slot = (tt * 4 + lh) ^ swz_l ^ (nj & 1);
            half8 bf = *(const half8*)&Bs[colr * 256 + slot * 8];
            acc[nj] = __builtin_amdgcn_mfma_f32_16x16x32_f16(af, bf, acc[nj], 0, 0, 0);
        }
    }

    // ---- Z store (D layout: col=l&15, row=(l>>4)*4+r) ----
#pragma unroll
    for (int r = 0; r < 4; ++r) {
        int grow = R0 + lh * 4 + r;
        if (grow < M) {
#pragma unroll
            for (int nj = 0; nj < FN; ++nj) {
                int col = nj * 16 + lr;
                if (col < NOUT) {
                    if constexpr (ZHALF)
                        ((_Float16*)Z)[(size_t)grow * NOUT + col] = (_Float16)acc[nj][r];
                    else
                        ((float*)Z)[(size_t)grow * NOUT + col] = acc[nj][r];
                }
            }
        }
    }

    if constexpr (FEL > 0) {
        float alv[FN];
#pragma unroll
        for (int nj = 0; nj < FN; ++nj) {
            int col = nj * 16 + lr;
            if constexpr (FEL == 1) alv[nj] = attn_flat[col];
            else                    alv[nj] = (col < NOUT) ? attn_flat[col] : 0.f;
        }
#pragma unroll
        for (int r = 0; r < 4; ++r) {
            float sh0 = 0.f, sh1 = 0.f, sh2 = 0.f, sh3 = 0.f;
#pragma unroll
            for (int nj = 0; nj < FN; ++nj) {
                float v = acc[nj][r] * alv[nj];
                if constexpr (FEL == 1) {
                    if constexpr (true) {
                        // head = nj>>2, compile-time
                        switch (nj >> 2) {
                            case 0: sh0 += v; break;
                            case 1: sh1 += v; break;
                            case 2: sh2 += v; break;
                            default: sh3 += v; break;
                        }
                    }
                } else {
                    int col = nj * 16 + lr;
                    int hs = col < 47 ? 0 : col < 94 ? 1 : col < 141 ? 2 : 3;
                    sh0 += (hs == 0) ? v : 0.f;
                    sh1 += (hs == 1) ? v : 0.f;
                    sh2 += (hs == 2) ? v : 0.f;
                    sh3 += (hs == 3) ? v : 0.f;
                }
            }
#pragma unroll
            for (int off = 1; off <= 8; off <<= 1) {
                sh0 += __shfl_xor(sh0, off); sh1 += __shfl_xor(sh1, off);
                sh2 += __shfl_xor(sh2, off); sh3 += __shfl_xor(sh3, off);
            }
            int grow = R0 + lh * 4 + r;
            if (lr == 0 && grow < M)
                *(float4*)(el + (size_t)grow * 4) = make_float4(sh0, sh1, sh2, sh3);
        }
    }
}

// er[m,h] = x[m,:] @ vrT[h,:]  (fp32 A); one wave per row
__global__ __launch_bounds__(256) void gemv_er_f32(const float* __restrict__ A,
        const float* __restrict__ vrT, float* __restrict__ er, int M) {
    int wv = threadIdx.x >> 6, lane = threadIdx.x & 63;
    int row = blockIdx.x * 4 + wv;
    if (row >= M) return;
    float4 xa = *(const float4*)(A + (size_t)row * IN + lane * 4);
    float s[4];
#pragma unroll
    for (int h = 0; h < 4; ++h) {
        float4 v = *(const float4*)(vrT + h * IN + lane * 4);
        s[h] = xa.x * v.x + xa.y * v.y + xa.z * v.z + xa.w * v.w;
    }
#pragma unroll
    for (int off = 32; off; off >>= 1)
#pragma unroll
        for (int h = 0; h < 4; ++h) s[h] += __shfl_xor(s[h], off);
    if (lane == 0) *(float4*)(er + (size_t)row * 4) = make_float4(s[0], s[1], s[2], s[3]);
}

// er from f16 A, rows < M
__global__ __launch_bounds__(256) void gemv_er_f16(const _Float16* __restrict__ A,
        const float* __restrict__ vrT, float* __restrict__ er, int M) {
    int wv = threadIdx.x >> 6, lane = threadIdx.x & 63;
    int row = blockIdx.x * 4 + wv;
    if (row >= M) return;
    half4 ah = *(const half4*)(A + (size_t)row * IN + lane * 4);
    float a0 = (float)ah[0], a1 = (float)ah[1], a2 = (float)ah[2], a3 = (float)ah[3];
    float s[4];
#pragma unroll
    for (int h = 0; h < 4; ++h) {
        float4 v = *(const float4*)(vrT + h * IN + lane * 4);
        s[h] = a0 * v.x + a1 * v.y + a2 * v.z + a3 * v.w;
    }
#pragma unroll
    for (int off = 32; off; off >>= 1)
#pragma unroll
        for (int h = 0; h < 4; ++h) s[h] += __shfl_xor(s[h], off);
    if (lane == 0) *(float4*)(er + (size_t)row * 4) = make_float4(s[0], s[1], s[2], s[3]);
}

__global__ void hist_k(const int* __restrict__ dst, int E, int* __restrict__ counts) {
    int i = blockIdx.x * blockDim.x + threadIdx.x;
    if (i < E) atomicAdd(&counts[dst[i]], 1);
}

// ---- 3-kernel parallel exclusive scan ----
__global__ __launch_bounds__(256) void scan1_k(const int* __restrict__ counts, int n,
                                               int* __restrict__ part) {
    __shared__ int ws[4];
    int i = blockIdx.x * 256 + threadIdx.x;
    int lane = threadIdx.x & 63, wv = threadIdx.x >> 6;
    int s = (i < n) ? counts[i] : 0;
#pragma unroll
    for (int off = 32; off; off >>= 1) s += __shfl_xor(s, off);
    if (lane == 0) ws[wv] = s;
    __syncthreads();
    if (threadIdx.x == 0) part[blockIdx.x] = ws[0] + ws[1] + ws[2] + ws[3];
}

__global__ __launch_bounds__(256) void scan2_k(int* __restrict__ part, int nb) {
    __shared__ int ws[4];
    int tid = threadIdx.x, lane = tid & 63, wv = tid >> 6;
    int v = (tid < nb) ? part[tid] : 0;
    int x = v;
#pragma unroll
    for (int off = 1; off < 64; off <<= 1) {
        int u = __shfl_up(x, off);
        if (lane >= off) x += u;
    }
    if (lane == 63) ws[wv] = x;
    __syncthreads();
    int base = 0;
    for (int k = 0; k < wv; ++k) base += ws[k];
    if (tid < nb) part[tid] = base + x - v;
}

__global__ __launch_bounds__(256) void scan3_k(const int* __restrict__ counts, int n,
        const int* __restrict__ part, int* __restrict__ offsets, int* __restrict__ cursor) {
    __shared__ int ws[4];
    int i = blockIdx.x * 256 + threadIdx.x;
    int lane = threadIdx.x & 63, wv = threadIdx.x >> 6;
    int v = (i < n) ? counts[i] : 0;
    int x = v;
#pragma unroll
    for (int off = 1; off < 64; off <<= 1) {
        int u = __shfl_up(x, off);
        if (lane >= off) x += u;
    }
    if (lane == 63) ws[wv] = x;
    __syncthreads();
    int base = part[blockIdx.x];
    for (int k = 0; k < wv; ++k) base += ws[k];
    int off_ = base + x - v;
    if (i < n) { offsets[i] = off_; cursor[i] = off_; }
    if (i == n - 1) offsets[n] = off_ + v;
}

__global__ void scatter_k(const int* __restrict__ src, const int* __restrict__ dst, int E,
        int* __restrict__ cursor, int* __restrict__ ssrc) {
    int i = blockIdx.x * blockDim.x + threadIdx.x;
    if (i < E) {
        int p = atomicAdd(&cursor[dst[i]], 1);
        ssrc[p] = src[i];
    }
}

// Layer-0 aggregation: 4 waves/block, 1 node/wave, index-prefetch + shfl broadcast
__global__ __launch_bounds__(256) void agg_l0(const int* __restrict__ ssrc,
        const int* __restrict__ offs, const float* __restrict__ el,
        const float* __restrict__ er, const _Float16* __restrict__ z,
        const float* __restrict__ bias, _Float16* __restrict__ h, int nd) {
    int wv = threadIdx.x >> 6, lane = threadIdx.x & 63;
    int d = blockIdx.x * 4 + wv;
    if (d >= nd) return;
    int head = lane >> 4;
    int beg = offs[d], end = offs[d + 1];
    float erh = er[(size_t)d * 4 + head];
    float ax = 0, ay = 0, az = 0, aw = 0, ssum = 0;
    for (int j0 = beg; j0 < end; j0 += 64) {
        int nn = min(64, end - j0);
        int myidx = (lane < nn) ? ssrc[j0 + lane] : 0;
        for (int j = 0; j < nn; ++j) {
            int s = __shfl(myidx, j);
            float e = el[(size_t)s * 4 + head] + erh;
            float wgt = __expf(leaky(e));
            ssum += wgt;
            half4 zv = *(const half4*)(z + (size_t)s * HD0 + lane * 4);
            ax += wgt * (float)zv[0]; ay += wgt * (float)zv[1];
            az += wgt * (float)zv[2]; aw += wgt * (float)zv[3];
        }
    }
    float inv = ssum > 0.f ? 1.f / ssum : 0.f;
    const float* b = bias + lane * 4;
    half4 o;
    o[0] = (_Float16)fmaxf(ax * inv + b[0], 0.f);
    o[1] = (_Float16)fmaxf(ay * inv + b[1], 0.f);
    o[2] = (_Float16)fmaxf(az * inv + b[2], 0.f);
    o[3] = (_Float16)fmaxf(aw * inv + b[3], 0.f);
    *(half4*)(h + (size_t)d * HD0 + lane * 4) = o;
}

// Layer-1 aggregation: 4 waves/block, 1 node/wave
__global__ __launch_bounds__(256) void agg_l1(const int* __restrict__ ssrc,
        const int* __restrict__ offs, const float* __restrict__ el,
        const float* __restrict__ er, const float* __restrict__ z,
        const float* __restrict__ bias, float* __restrict__ out, int nd) {
    int wv = threadIdx.x >> 6, lane = threadIdx.x & 63;
    int d = blockIdx.x * 4 + wv;
    if (d >= nd) return;
    int beg = offs[d], end = offs[d + 1];
    float4 er4 = *(const float4*)(er + (size_t)d * 4);
    const int f0 = lane, f1 = lane + 64, f2 = lane + 128;
    const int h0 = f0 / NCLS, h1 = f1 / NCLS;
    const bool has2 = f2 < HD1;
    const int h2 = has2 ? f2 / NCLS : 3;
    float a0 = 0, a1 = 0, a2 = 0;
    float s0 = 0, s1 = 0, s2 = 0, s3 = 0;
    for (int j0 = beg; j0 < end; j0 += 64) {
        int nn = min(64, end - j0);
        int myidx = (lane < nn) ? ssrc[j0 + lane] : 0;
        for (int j = 0; j < nn; ++j) {
            int s = __shfl(myidx, j);
            float4 e4 = *(const float4*)(el + (size_t)s * 4);
            float w0 = __expf(leaky(e4.x + er4.x));
            float w1 = __expf(leaky(e4.y + er4.y));
            float w2 = __expf(leaky(e4.z + er4.z));
            float w3 = __expf(leaky(e4.w + er4.w));
            s0 += w0; s1 += w1; s2 += w2; s3 += w3;
            const float* zr = z + (size_t)s * HD1;
            a0 += (h0 == 0 ? w0 : h0 == 1 ? w1 : h0 == 2 ? w2 : w3) * zr[f0];
            a1 += (h1 == 0 ? w0 : h1 == 1 ? w1 : h1 == 2 ? w2 : w3) * zr[f1];
            if (has2) a2 += (h2 == 0 ? w0 : h2 == 1 ? w1 : h2 == 2 ? w2 : w3) * zr[f2];
        }
    }
    float sa = h0 == 0 ? s0 : h0 == 1 ? s1 : h0 == 2 ? s2 : s3;
    float sb = h1 == 0 ? s0 : h1 == 1 ? s1 : h1 == 2 ? s2 : s3;
    float sc = h2 == 0 ? s0 : h2 == 1 ? s1 : h2 == 2 ? s2 : s3;
    float* orow = out + (size_t)d * HD1;
    orow[f0] = a0 * (sa > 0.f ? 1.f / sa : 0.f) + bias[f0];
    orow[f1] = a1 * (sb > 0.f ? 1.f / sb : 0.f) + bias[f1];
    if (has2) orow[f2] = a2 * (sc > 0.f ? 1.f / sc : 0.f) + bias[f2];
}

// mean over heads + log_softmax; one wave per node
__global__ __launch_bounds__(256) void final_k(const float* __restrict__ o1,
        float* __restrict__ y, int n) {
    int wave = threadIdx.x >> 6, lane = threadIdx.x & 63;
    int node = blockIdx.x * 4 + wave;
    if (node >= n) return;
    const float* r = o1 + (size_t)node * HD1;
    float vv = 0.f, v = -INFINITY;
    if (lane < NCLS) {
        vv = 0.25f * (r[lane] + r[lane + NCLS] + r[lane + 2 * NCLS] + r[lane + 3 * NCLS]);
        v = vv;
    }
    float mx = v;
#pragma unroll
    for (int off = 32; off; off >>= 1) mx = fmaxf(mx, __shfl_xor(mx, off));
    float p = (lane < NCLS) ? __expf(vv - mx) : 0.f;
    float sum = p;
#pragma unroll
    for (int off = 32; off; off >>= 1) sum += __shfl_xor(sum, off);
    if (lane < NCLS) y[(size_t)node * NCLS + lane] = vv - mx - logf(sum);
}

extern "C" void kernel_launch(void* const* d_in, const int* in_sizes, int n_in,
                              void* d_out, int out_size, void* d_ws, size_t ws_size,
                              hipStream_t stream) {
    const float* x    = (const float*)d_in[0];
    const int*   src0 = (const int*)d_in[1];
    const int*   dst0 = (const int*)d_in[2];
    const int*   src1 = (const int*)d_in[3];
    const int*   dst1 = (const int*)d_in[4];
    const float* W0s  = (const float*)d_in[7];
    const float* W0d  = (const float*)d_in[8];
    const float* al0  = (const float*)d_in[9];
    const float* ar0  = (const float*)d_in[10];
    const float* b0   = (const float*)d_in[11];
    const float* W1s  = (const float*)d_in[12];
    const float* W1d  = (const float*)d_in[13];
    const float* al1  = (const float*)d_in[14];
    const float* ar1  = (const float*)d_in[15];
    const float* b1   = (const float*)d_in[16];
    const int E0 = in_sizes[1], E1 = in_sizes[3];
    const int NS0 = in_sizes[0] / IN;

    char* p = (char*)d_ws;
    auto take = [&](size_t bytes) {
        char* r = p;
        p += (bytes + 255) & ~(size_t)255;
        return r;
    };
    _Float16* z0  = (_Float16*)take((size_t)NS0 * HD0 * 2);
    _Float16* h   = (_Float16*)take((size_t)ND0 * HD0 * 2);
    float*    z1  = (float*)take((size_t)ND0 * HD1 * 4);
    float*    o1  = (float*)take((size_t)ND1 * HD1 * 4);
    float*    el0 = (float*)take((size_t)NS0 * 4 * 4);
    float*    er0 = (float*)take((size_t)ND0 * 4 * 4);
    float*    el1 = (float*)take((size_t)ND0 * 4 * 4);
    float*    er1 = (float*)take((size_t)ND1 * 4 * 4);
    _Float16* B0t = (_Float16*)take((size_t)256 * IN * 2);
    _Float16* B1t = (_Float16*)take((size_t)192 * IN * 2);
    float*    vr0T = (float*)take(4 * IN * 4);
    float*    vr1T = (float*)take(4 * IN * 4);
    int* counts0 = (int*)take((size_t)ND0 * 4);
    int* offs0   = (int*)take((size_t)(ND0 + 1) * 4);
    int* cur0    = (int*)take((size_t)ND0 * 4);
    int* ss0     = (int*)take((size_t)E0 * 4);
    int* counts1 = (int*)take((size_t)ND1 * 4);
    int* offs1   = (int*)take((size_t)(ND1 + 1) * 4);
    int* cur1    = (int*)take((size_t)ND1 * 4);
    int* ss1     = (int*)take((size_t)E1 * 4);
    int* part0   = (int*)take(256 * 4);
    int* part1   = (int*)take(256 * 4);

    const int NB0 = (ND0 + 255) / 256, NB1 = (ND1 + 255) / 256;

    hipMemsetAsync(counts0, 0, (size_t)ND0 * 4, stream);
    hipMemsetAsync(counts1, 0, (size_t)ND1 * 4, stream);

    make_vT<<<4, 256, 0, stream>>>(W0d, ar0, vr0T, HID);
    make_vT<<<4, 256, 0, stream>>>(W1d, ar1, vr1T, NCLS);
    cvtB<<<256, 256, 0, stream>>>(W0s, B0t, HD0, 256);
    cvtB<<<192, 256, 0, stream>>>(W1s, B1t, HD1, 192);

    // ---- layer 0 ----
    gemm_stream<false, 256, 256, true, 1><<<(NS0 + 127) / 128, 512, 0, stream>>>(
        (const void*)x, B0t, (void*)z0, al0, el0, NS0);
    gemv_er_f32<<<(ND0 + 3) / 4, 256, 0, stream>>>(x, vr0T, er0, ND0);
    hist_k<<<(E0 + 255) / 256, 256, 0, stream>>>(dst0, E0, counts0);
    scan1_k<<<NB0, 256, 0, stream>>>(counts0, ND0, part0);
    scan2_k<<<1, 256, 0, stream>>>(part0, NB0);
    scan3_k<<<NB0, 256, 0, stream>>>(counts0, ND0, part0, offs0, cur0);
    scatter_k<<<(E0 + 255) / 256, 256, 0, stream>>>(src0, dst0, E0, cur0, ss0);
    agg_l0<<<(ND0 + 3) / 4, 256, 0, stream>>>(ss0, offs0, el0, er0, z0, b0, h, ND0);

    // ---- layer 1 ----
    gemm_stream<true, 192, 188, false, 2><<<(ND0 + 127) / 128, 512, 0, stream>>>(
        (const void*)h, B1t, (void*)z1, al1, el1, ND0);
    gemv_er_f16<<<(ND1 + 3) / 4, 256, 0, stream>>>(h, vr1T, er1, ND1);
    hist_k<<<(E1 + 255) / 256, 256, 0, stream>>>(dst1, E1, counts1);
    scan1_k<<<NB1, 256, 0, stream>>>(counts1, ND1, part1);
    scan2_k<<<1, 256, 0, stream>>>(part1, NB1);
    scan3_k<<<NB1, 256, 0, stream>>>(counts1, ND1, part1, offs1, cur1);
    scatter_k<<<(E1 + 255) / 256, 256, 0, stream>>>(src1, dst1, E1, cur1, ss1);
    agg_l1<<<(ND1 + 3) / 4, 256, 0, stream>>>(ss1, offs1, el1, er1, z1, b1, o1, ND1);

    final_k<<<(ND1 + 3) / 4, 256, 0, stream>>>(o1, (float*)d_out, ND1);
}